// Round 1
// baseline (112.539 us; speedup 1.0000x reference)
//
#include <hip/hip_runtime.h>
#include <hip/hip_fp16.h>
#include <stdint.h>

#define D0 1024
#define D1 8192
#define D2 8192
#define D3 10240
#define NGATES (D1 + D2 + D3)   // 26624
#define B_ROWS 4096

// LDS layout (bytes): xb 8192 | h1 65536 | h2 65536 | csum 160
#define SMEM_XB    0
#define SMEM_H1    8192
#define SMEM_H2    (8192 + 65536)
#define SMEM_CSUM  (8192 + 65536 + 65536)
#define SMEM_BYTES (8192 + 65536 + 65536 + 160)

__device__ __constant__ float OPC[16][4] = {
    {0.f, 0.f, 0.f, 0.f}, {0.f, 0.f, 0.f, 1.f}, {0.f, 1.f, 0.f, -1.f}, {0.f, 1.f, 0.f, 0.f},
    {0.f, 0.f, 1.f, -1.f}, {0.f, 0.f, 1.f, 0.f}, {0.f, 1.f, 1.f, -2.f}, {0.f, 1.f, 1.f, -1.f},
    {1.f, -1.f, -1.f, 1.f}, {1.f, -1.f, -1.f, 2.f}, {1.f, 0.f, -1.f, 0.f}, {1.f, 0.f, -1.f, 1.f},
    {1.f, -1.f, 0.f, 0.f}, {1.f, -1.f, 0.f, 1.f}, {1.f, 0.f, 0.f, -1.f}, {1.f, 0.f, 0.f, 0.f}};

// Pre-pass: per gate, softmax(w[16]) @ OP_COEF -> 4 coefs (fp16x4), plus packed
// gather indices (u16|u16). Row-invariant, so computed once per launch.
__global__ void prep_kernel(const float* __restrict__ w1, const float* __restrict__ w2,
                            const float* __restrict__ w3,
                            const int* __restrict__ ia1, const int* __restrict__ ib1,
                            const int* __restrict__ ia2, const int* __restrict__ ib2,
                            const int* __restrict__ ia3, const int* __restrict__ ib3,
                            uint2* __restrict__ coef_ws, uint32_t* __restrict__ idx_ws) {
    int G = blockIdx.x * blockDim.x + threadIdx.x;
    if (G >= NGATES) return;
    const float* w;
    int ia, ib;
    if (G < D1) {
        w = w1 + (size_t)G * 16; ia = ia1[G]; ib = ib1[G];
    } else if (G < D1 + D2) {
        int g = G - D1;
        w = w2 + (size_t)g * 16; ia = ia2[g]; ib = ib2[g];
    } else {
        int g = G - D1 - D2;
        w = w3 + (size_t)g * 16; ia = ia3[g]; ib = ib3[g];
    }
    float e[16];
    float m = w[0];
#pragma unroll
    for (int i = 1; i < 16; ++i) m = fmaxf(m, w[i]);
    float s = 0.f;
#pragma unroll
    for (int i = 0; i < 16; ++i) { e[i] = expf(w[i] - m); s += e[i]; }
    float inv = 1.f / s;
    float c0 = 0.f, c1 = 0.f, c2 = 0.f, c3 = 0.f;
#pragma unroll
    for (int i = 0; i < 16; ++i) {
        float p = e[i] * inv;
        c0 += p * OPC[i][0];
        c1 += p * OPC[i][1];
        c2 += p * OPC[i][2];
        c3 += p * OPC[i][3];
    }
    uint2 cv;
    cv.x = __builtin_bit_cast(uint32_t, __floats2half2_rn(c0, c1));  // (c0,c1)
    cv.y = __builtin_bit_cast(uint32_t, __floats2half2_rn(c2, c3));  // (c2,c3)
    coef_ws[G] = cv;
    idx_ws[G] = (uint32_t)ia | ((uint32_t)ib << 16);
}

// Evaluate one gate for 4 rows packed as 2x half2. h = c0 + c1*a + c2*b + c3*a*b
//   = (c0 + c2*b) + a*(c1 + c3*b)  -> 3 pk_fma per row-pair.
__device__ __forceinline__ uint2 gate4(uint2 av, uint2 bv, uint2 cf) {
    __half2 a01 = __builtin_bit_cast(__half2, av.x);
    __half2 a23 = __builtin_bit_cast(__half2, av.y);
    __half2 b01 = __builtin_bit_cast(__half2, bv.x);
    __half2 b23 = __builtin_bit_cast(__half2, bv.y);
    __half2 lo = __builtin_bit_cast(__half2, cf.x);
    __half2 hi = __builtin_bit_cast(__half2, cf.y);
    __half2 c0 = __low2half2(lo), c1 = __high2half2(lo);
    __half2 c2 = __low2half2(hi), c3 = __high2half2(hi);
    __half2 h01 = __hfma2(a01, __hfma2(b01, c3, c1), __hfma2(b01, c2, c0));
    __half2 h23 = __hfma2(a23, __hfma2(b23, c3, c1), __hfma2(b23, c2, c0));
    uint2 r;
    r.x = __builtin_bit_cast(uint32_t, h01);
    r.y = __builtin_bit_cast(uint32_t, h23);
    return r;
}

// Fused 3-layer + group-sum kernel. One block = 4 batch rows; activations live
// in LDS, row-interleaved [gate][4 rows] fp16 so one ds_read_b64 feeds 4 rows.
__global__ __launch_bounds__(1024, 4) void fused_kernel(
    const float* __restrict__ x, const uint2* __restrict__ coef_ws,
    const uint32_t* __restrict__ idx_ws, float* __restrict__ out) {
    extern __shared__ char smem[];
    uint2* xb = (uint2*)(smem + SMEM_XB);    // [1024] gates x 4 rows fp16
    uint2* h1 = (uint2*)(smem + SMEM_H1);    // [8192]
    uint2* h2 = (uint2*)(smem + SMEM_H2);    // [8192]
    float* csum = (float*)(smem + SMEM_CSUM);  // [10 classes][4 rows]

    const int t = threadIdx.x;
    const int rowbase = blockIdx.x << 2;  // 4 rows per block

    // Stage A: load 4 rows of x (coalesced), convert fp16, interleave by row.
    {
        const float* xp = x + (size_t)rowbase * D0 + t;
        float v0 = xp[0];
        float v1 = xp[D0];
        float v2 = xp[2 * D0];
        float v3 = xp[3 * D0];
        uint2 v;
        v.x = __builtin_bit_cast(uint32_t, __floats2half2_rn(v0, v1));
        v.y = __builtin_bit_cast(uint32_t, __floats2half2_rn(v2, v3));
        xb[t] = v;
    }
    if (t < 40) csum[t] = 0.f;
    __syncthreads();

    // Stage B: layer 1 (8192 gates, gather from xb)
#pragma unroll
    for (int k = 0; k < 8; ++k) {
        int g = t + (k << 10);
        uint32_t ip = idx_ws[g];
        uint2 cf = coef_ws[g];
        h1[g] = gate4(xb[ip & 0xffffu], xb[ip >> 16], cf);
    }
    __syncthreads();

    // Stage C: layer 2 (8192 gates, gather from h1)
#pragma unroll
    for (int k = 0; k < 8; ++k) {
        int g = t + (k << 10);
        uint32_t ip = idx_ws[D1 + g];
        uint2 cf = coef_ws[D1 + g];
        h2[g] = gate4(h1[ip & 0xffffu], h1[ip >> 16], cf);
    }
    __syncthreads();

    // Stage D: layer 3 + grouped sum. Each wave owns 640 contiguous gates
    // (spans at most 2 classes; 64-gate chunks never straddle a class
    // boundary since 1024 % 64 == 0 -> wave-uniform class select).
    {
        const int wv = t >> 6, lane = t & 63;
        const int gbase = wv * 640;
        const int cA = gbase >> 10;
        const int bnd = (cA + 1) << 10;
        float s0[4] = {0.f, 0.f, 0.f, 0.f};
        float s1[4] = {0.f, 0.f, 0.f, 0.f};
#pragma unroll
        for (int j = 0; j < 10; ++j) {
            int gc = gbase + (j << 6);
            int g = gc + lane;
            uint32_t ip = idx_ws[D1 + D2 + g];
            uint2 cf = coef_ws[D1 + D2 + g];
            uint2 hv = gate4(h2[ip & 0xffffu], h2[ip >> 16], cf);
            __half2 h01 = __builtin_bit_cast(__half2, hv.x);
            __half2 h23 = __builtin_bit_cast(__half2, hv.y);
            float f0 = __low2float(h01), f1 = __high2float(h01);
            float f2 = __low2float(h23), f3 = __high2float(h23);
            if (gc < bnd) {
                s0[0] += f0; s0[1] += f1; s0[2] += f2; s0[3] += f3;
            } else {
                s1[0] += f0; s1[1] += f1; s1[2] += f2; s1[3] += f3;
            }
        }
        // wave butterfly reduction (64 lanes)
#pragma unroll
        for (int m = 1; m < 64; m <<= 1) {
#pragma unroll
            for (int r = 0; r < 4; ++r) {
                s0[r] += __shfl_xor(s0[r], m, 64);
                s1[r] += __shfl_xor(s1[r], m, 64);
            }
        }
        if (lane == 0) {
#pragma unroll
            for (int r = 0; r < 4; ++r) atomicAdd(&csum[cA * 4 + r], s0[r]);
            if (gbase + 640 > bnd) {
#pragma unroll
                for (int r = 0; r < 4; ++r) atomicAdd(&csum[(cA + 1) * 4 + r], s1[r]);
            }
        }
    }
    __syncthreads();

    if (t < 40) {
        int c = t >> 2, r = t & 3;
        out[(size_t)(rowbase + r) * 10 + c] = csum[t] * (1.0f / 30.0f);
    }
}

extern "C" void kernel_launch(void* const* d_in, const int* in_sizes, int n_in,
                              void* d_out, int out_size, void* d_ws, size_t ws_size,
                              hipStream_t stream) {
    const float* x = (const float*)d_in[0];
    const float* w1 = (const float*)d_in[1];
    const float* w2 = (const float*)d_in[2];
    const float* w3 = (const float*)d_in[3];
    const int* ia1 = (const int*)d_in[4];
    const int* ib1 = (const int*)d_in[5];
    const int* ia2 = (const int*)d_in[6];
    const int* ib2 = (const int*)d_in[7];
    const int* ia3 = (const int*)d_in[8];
    const int* ib3 = (const int*)d_in[9];
    float* out = (float*)d_out;

    uint2* coef_ws = (uint2*)d_ws;                                        // 26624 * 8 B
    uint32_t* idx_ws = (uint32_t*)((char*)d_ws + (size_t)NGATES * 8);     // 26624 * 4 B

    // >64KB dynamic LDS needs the opt-in (host-side call; graph-capture safe).
    hipFuncSetAttribute(reinterpret_cast<const void*>(fused_kernel),
                        hipFuncAttributeMaxDynamicSharedMemorySize, SMEM_BYTES);

    prep_kernel<<<(NGATES + 255) / 256, 256, 0, stream>>>(
        w1, w2, w3, ia1, ib1, ia2, ib2, ia3, ib3, coef_ws, idx_ws);
    fused_kernel<<<B_ROWS / 4, 1024, SMEM_BYTES, stream>>>(x, coef_ws, idx_ws, out);
}